// Round 14
// baseline (246.600 us; speedup 1.0000x reference)
//
#include <hip/hip_runtime.h>

#define KDIM 256
#define DWIN 20
#define NOBS 8192
#define TAU  20
#define TROWS (NOBS - TAU)          // 8172
#define KTOT  (DWIN * KDIM)         // 5120
#define KS128 (KTOT / 128)          // 40 K-steps of 128
#define QS128 (KS128 / 4)           // 10 per wave (K-quarter)

#define BM 64
#define NBLK_M ((TROWS + BM - 1) / BM)   // 128
#define NBLK   (NBLK_M * 4)              // 512 -> 2 blocks/CU

#define AROWS 83                     // 64 + DWIN - 1
#define APITCH 272                   // 256B data + 16B pad (2-way bank alias = free)

#define PC_BYTES  65536
#define SRED_OFF  PC_BYTES
#define DYN_TOTAL (PC_BYTES + 64)

typedef float f32x4 __attribute__((ext_vector_type(4)));
typedef int   i32x4 __attribute__((ext_vector_type(4)));
typedef int   i32x8 __attribute__((ext_vector_type(8)));

// ws layout (bytes)
#define WS_BF    0u
#define WS_A8    2097152u
#define WS_D1    (8u*1024*1024)
#define WS_D2    (16u*1024*1024)
#define WS_D3    (24u*1024*1024)     // lam scatter ~8.5MB + slots
#define WS_D3LL  (40u*1024*1024)
#define WS_NEED  (96u*1024*1024)

__device__ __forceinline__ i32x8 join8(i32x4 a, i32x4 b) {
    i32x8 r;
    r[0]=a[0]; r[1]=a[1]; r[2]=a[2]; r[3]=a[3];
    r[4]=b[0]; r[5]=b[1]; r[6]=b[2]; r[7]=b[3];
    return r;
}

__device__ __forceinline__ unsigned int pk4_fp8(float a, float b, float c, float d) {
    int lo = __builtin_amdgcn_cvt_pk_fp8_f32(a, b, 0, false);
    return (unsigned int)__builtin_amdgcn_cvt_pk_fp8_f32(c, d, lo, true);
}

// ---- prep: blocks [0,256) B-fragments; [256,320) A8 pack (verified R12/R13) ----
__global__ __launch_bounds__(256)
void prep_kernel(const float* __restrict__ beta1,
                 const float* __restrict__ obs,
                 unsigned char* __restrict__ Bf8,
                 unsigned int* __restrict__ A8,
                 float* __restrict__ out)
{
    const int tid = threadIdx.x;
    if (blockIdx.x >= KDIM) {
        const int base = (blockIdx.x - KDIM) * 8192;
#pragma unroll 4
        for (int u = tid; u < 8192; u += 256) {
            float4 v = ((const float4*)obs)[base + u];
            A8[base + u] = pk4_fp8(v.x, v.y, v.z, v.w);
        }
        return;
    }

    __shared__ float L[KDIM * 21];
    const int n = blockIdx.x;
    if (n == 0 && tid == 0) out[0] = 0.f;

    const float* __restrict__ src = beta1 + (size_t)n * KTOT;
    for (int f = tid; f < KTOT; f += 256)
        L[(f / DWIN) * 21 + (f % DWIN)] = src[f];
    __syncthreads();

    const int nt = n >> 4, qn = n & 15;
    for (int c = tid; c < KS128 * 8; c += 256) {
        const int ks = c >> 3, g = (c >> 1) & 3, half = c & 1;
        const int kb = ks * 128 + g * 32 + half * 16;
        i32x4 w;
#pragma unroll
        for (int u = 0; u < 4; ++u) {
            const int k0 = kb + u * 4;
            w[u] = (int)pk4_fp8(L[((k0+0) & 255) * 21 + ((k0+0) >> 8)],
                                L[((k0+1) & 255) * 21 + ((k0+1) >> 8)],
                                L[((k0+2) & 255) * 21 + ((k0+2) >> 8)],
                                L[((k0+3) & 255) * 21 + ((k0+3) >> 8)]);
        }
        *(i32x4*)&Bf8[(((size_t)ks * 16 + nt) * 64 + g * 16 + qn) * 32 + half * 16] = w;
    }
}

extern __shared__ char dynlds[];

// ---- templated GEMM. DIAG: 0=real, 1=stage-only, 2=stage+kloop, 3=+epilogue ----
template<int RS, int RK, int RE, int DIAG>
__global__ __launch_bounds__(256, 2)
void gemm_t(const float* __restrict__ obs,
            const float* __restrict__ beta0,
            const unsigned char* __restrict__ Bf8,
            const unsigned char* __restrict__ A8,
            float* __restrict__ out,
            float* __restrict__ diag)
{
    const int tid  = threadIdx.x;
    const int lane = tid & 63;
    const int kq   = tid >> 6;
    const int g = lane >> 4;
    const int q = lane & 15;
    const int nb = blockIdx.x & 3;
    const int mb = blockIdx.x >> 2;
    const int i0 = mb * BM;

    char* ldsA8 = dynlds;
    const char* bbase = (const char*)Bf8 + (size_t)(nb * 4) * 2048 + (size_t)lane * 32;

// direct 32B-aligned i32x8 load (removes join8 movs for B)
#define LOADB8(dst, s)                                                           \
    {                                                                            \
        const char* _p = bbase + (size_t)(10 * kq + ((s) < QS128 ? (s) : QS128 - 1)) * 32768; \
        _Pragma("unroll")                                                        \
        for (int t = 0; t < 4; ++t)                                              \
            dst[t] = *(const i32x8*)(_p + t * 2048);                             \
    }

    i32x8 rbA[4], rbB[4];
    if constexpr (RK > 0) { LOADB8(rbA, 0) }

    // --- stage A panel from A8 (coalesced 16B-chunk copy, R13-proven) ---
#pragma unroll 1
    for (int rs = 0; rs < RS; ++rs) {
        for (int idx = tid; idx < AROWS * 16; idx += 256) {
            const int row = idx >> 4, c16 = idx & 15;
            const int grow = min(i0 + row, NOBS - 1);
            i32x4 v = *(const i32x4*)(A8 + (size_t)grow * 256 + c16 * 16);
            *(i32x4*)(ldsA8 + row * APITCH + c16 * 16) = v;
        }
        if constexpr (RS > 1) asm volatile("" ::: "memory");
    }
    __syncthreads();

    if constexpr (DIAG == 1) {
        int v = *(const int*)(ldsA8 + tid * 4);
        diag[(size_t)blockIdx.x * 256 + tid] = (float)v;
        return;
    }

    f32x4 acc[4][4];
#pragma unroll
    for (int m = 0; m < 4; ++m)
#pragma unroll
        for (int t = 0; t < 4; ++t)
            acc[m][t] = (f32x4){0.f, 0.f, 0.f, 0.f};

#define COMPUTE8(s, breg)                                                        \
    {                                                                            \
        const int _ks = 10 * kq + (s);                                           \
        const int _aro  = _ks >> 1;                                              \
        const int _acol = (_ks & 1) * 128 + g * 32;                              \
        i32x8 _af[4];                                                            \
        _Pragma("unroll")                                                        \
        for (int m = 0; m < 4; ++m) {                                            \
            const char* _ap = ldsA8 + (m * 16 + q + _aro) * APITCH + _acol;      \
            i32x4 _lo = *(const i32x4*)_ap;                                      \
            i32x4 _hi = *(const i32x4*)(_ap + 16);                               \
            _af[m] = join8(_lo, _hi);                                            \
        }                                                                        \
        _Pragma("unroll")                                                        \
        for (int t = 0; t < 4; ++t)                                              \
            _Pragma("unroll")                                                    \
            for (int m = 0; m < 4; ++m)                                          \
                acc[m][t] = __builtin_amdgcn_mfma_scale_f32_16x16x128_f8f6f4(    \
                    _af[m], (breg)[t], acc[m][t], 0, 0, 0, 0x7f, 0, 0x7f);       \
    }

#pragma unroll 1
    for (int rk = 0; rk < RK; ++rk) {
        if (rk > 0) { LOADB8(rbA, 0) }
#pragma unroll 1
        for (int s = 0; s < QS128; s += 2) {
            LOADB8(rbB, s + 1)
            COMPUTE8(s, rbA)
            if (s + 2 < QS128) LOADB8(rbA, s + 2)
            COMPUTE8(s + 1, rbB)
        }
        if constexpr (RK > 1) asm volatile("" ::: "memory");
    }

    if constexpr (DIAG == 2) {
        f32x4 ssum = (f32x4){0.f, 0.f, 0.f, 0.f};
#pragma unroll
        for (int m = 0; m < 4; ++m)
#pragma unroll
            for (int t = 0; t < 4; ++t)
                ssum += acc[m][t];
        *(f32x4*)&diag[((size_t)blockIdx.x * 256 + tid) * 4] = ssum;
        return;
    }

    // ---- epilogue (RE reps; real RE=1 dst=out) ----
#pragma unroll 1
    for (int re = 0; re < RE; ++re) {
        float* dst = (DIAG == 3) ? (diag + (size_t)re * 1024) : out;
        __syncthreads();
        f32x4* pc = (f32x4*)dynlds;
#pragma unroll
        for (int m = 0; m < 4; ++m)
#pragma unroll
            for (int t = 0; t < 4; ++t)
                pc[((kq * 16 + m * 4 + t) << 6) + lane] = acc[m][t];
        __syncthreads();

        double part = 0.0;
#pragma unroll
        for (int t = 0; t < 4; ++t) {
            f32x4 sum = pc[((kq * 4 + t) << 6) + lane];
#pragma unroll
            for (int wp = 1; wp < 4; ++wp)
                sum += pc[((wp * 16 + kq * 4 + t) << 6) + lane];
            const int col = nb * 64 + t * 16 + q;
            const float b0v = beta0[col];
#pragma unroll
            for (int r = 0; r < 4; ++r) {
                const int row = i0 + kq * 16 + 4 * g + r;   // C/D: row=(lane>>4)*4+reg
                if (row < TROWS) {
                    float lam = sum[r] + b0v;
                    dst[1 + (size_t)row * KDIM + col] = lam;
                    float o = obs[(size_t)(row + TAU) * KDIM + col];
                    part += (double)o * (double)__logf(lam) - (double)lam;
                }
            }
        }

#pragma unroll
        for (int off = 32; off > 0; off >>= 1) part += __shfl_down(part, off, 64);
        double* sred = (double*)(dynlds + SRED_OFF);
        if (lane == 0) sred[kq] = part;
        __syncthreads();
        if constexpr (DIAG == 0) {
            if (tid == 0)
                atomicAdd(out, (float)(sred[0] + sred[1] + sred[2] + sred[3]));
        } else {
            float* ll = (float*)((char*)diag + (WS_D3LL - WS_D3));
            if (tid == 0)
                ll[(size_t)re * NBLK + blockIdx.x] =
                    (float)(sred[0] + sred[1] + sred[2] + sred[3]);
            asm volatile("" ::: "memory");
        }
    }
}

// ================= fallback fp32 path (R1, proven) =================
#define BM_OLD 16
#define NBLK_OLD ((TROWS + BM_OLD - 1) / BM_OLD)   // 511

__global__ __launch_bounds__(KDIM, 2)
void old_lam_kernel(const float* __restrict__ obs,
                    const float* __restrict__ beta0,
                    const float* __restrict__ beta1,
                    float* __restrict__ out,
                    double* __restrict__ partials)
{
    const int k  = threadIdx.x;
    const int i0 = blockIdx.x * BM_OLD;
    const int nr = min(BM_OLD, TROWS - i0);
    const int smax = nr + DWIN - 1;

    float acc[BM_OLD];
#pragma unroll
    for (int r = 0; r < BM_OLD; ++r) acc[r] = 0.f;

    const float* __restrict__ b1k = beta1 + (size_t)k * (KDIM * DWIN);

    for (int b = 0; b < KDIM; ++b) {
        float br[DWIN];
        const float4* qd = (const float4*)(b1k + b * DWIN);
#pragma unroll
        for (int v = 0; v < DWIN / 4; ++v) {
            float4 t = qd[v];
            br[4*v+0] = t.x; br[4*v+1] = t.y; br[4*v+2] = t.z; br[4*v+3] = t.w;
        }
        float wv[BM_OLD + DWIN - 1];
#pragma unroll
        for (int s = 0; s < BM_OLD + DWIN - 1; ++s)
            wv[s] = (s < smax) ? obs[(size_t)(i0 + s) * KDIM + b] : 0.f;
#pragma unroll
        for (int r = 0; r < BM_OLD; ++r)
#pragma unroll
            for (int a = 0; a < DWIN; ++a)
                acc[r] = fmaf(wv[r + a], br[a], acc[r]);
    }

    const float b0 = beta0[k];
    double part = 0.0;
    for (int r = 0; r < nr; ++r) {
        float lam = acc[r] + b0;
        out[1 + (size_t)(i0 + r) * KDIM + k] = lam;
        float o = obs[(size_t)(i0 + r + TAU) * KDIM + k];
        part += (double)(o * logf(lam) - lam);
    }

    __shared__ double sred2[KDIM];
    sred2[k] = part;
    __syncthreads();
    for (int off = KDIM / 2; off > 0; off >>= 1) {
        if (k < off) sred2[k] += sred2[k + off];
        __syncthreads();
    }
    if (k == 0) partials[blockIdx.x] = sred2[0];
}

__global__ void reduce_final_kernel(const double* __restrict__ partials,
                                    float* __restrict__ out, int n)
{
    __shared__ double sr[256];
    double v = 0.0;
    for (int i = threadIdx.x; i < n; i += 256) v += partials[i];
    sr[threadIdx.x] = v;
    __syncthreads();
    for (int off = 128; off > 0; off >>= 1) {
        if (threadIdx.x < off) sr[threadIdx.x] += sr[threadIdx.x + off];
        __syncthreads();
    }
    if (threadIdx.x == 0) out[0] = (float)sr[0];
}
// ===================================================================

extern "C" void kernel_launch(void* const* d_in, const int* in_sizes, int n_in,
                              void* d_out, int out_size, void* d_ws, size_t ws_size,
                              hipStream_t stream)
{
    const float* obs   = (const float*)d_in[0];
    const float* beta0 = (const float*)d_in[1];
    const float* beta1 = (const float*)d_in[2];
    float* out = (float*)d_out;

    if (ws_size >= (size_t)WS_NEED) {
        unsigned char* Bf8 = (unsigned char*)d_ws + WS_BF;
        unsigned int*  A8  = (unsigned int*)((char*)d_ws + WS_A8);
        float* d1 = (float*)((char*)d_ws + WS_D1);
        float* d2 = (float*)((char*)d_ws + WS_D2);
        float* d3 = (float*)((char*)d_ws + WS_D3);

        (void)hipFuncSetAttribute(reinterpret_cast<const void*>(&gemm_t<1,1,1,0>),
                                  hipFuncAttributeMaxDynamicSharedMemorySize, DYN_TOTAL);
        (void)hipFuncSetAttribute(reinterpret_cast<const void*>(&gemm_t<32,0,0,1>),
                                  hipFuncAttributeMaxDynamicSharedMemorySize, DYN_TOTAL);
        (void)hipFuncSetAttribute(reinterpret_cast<const void*>(&gemm_t<1,16,0,2>),
                                  hipFuncAttributeMaxDynamicSharedMemorySize, DYN_TOTAL);
        (void)hipFuncSetAttribute(reinterpret_cast<const void*>(&gemm_t<1,1,24,3>),
                                  hipFuncAttributeMaxDynamicSharedMemorySize, DYN_TOTAL);

        hipLaunchKernelGGL(prep_kernel, dim3(KDIM + 64), dim3(256), 0, stream,
                           beta1, obs, Bf8, A8, out);
        hipLaunchKernelGGL((gemm_t<1,1,1,0>), dim3(NBLK), dim3(256), DYN_TOTAL, stream,
                           obs, beta0, Bf8, (const unsigned char*)A8, out, (float*)nullptr);
        // diagnostics (ws only)
        hipLaunchKernelGGL((gemm_t<32,0,0,1>), dim3(NBLK), dim3(256), DYN_TOTAL, stream,
                           obs, beta0, Bf8, (const unsigned char*)A8, out, d1);
        hipLaunchKernelGGL((gemm_t<1,16,0,2>), dim3(NBLK), dim3(256), DYN_TOTAL, stream,
                           obs, beta0, Bf8, (const unsigned char*)A8, out, d2);
        hipLaunchKernelGGL((gemm_t<1,1,24,3>), dim3(NBLK), dim3(256), DYN_TOTAL, stream,
                           obs, beta0, Bf8, (const unsigned char*)A8, out, d3);
    } else {
        double* partials = (double*)d_ws;
        hipLaunchKernelGGL(old_lam_kernel, dim3(NBLK_OLD), dim3(KDIM), 0, stream,
                           obs, beta0, beta1, out, partials);
        hipLaunchKernelGGL(reduce_final_kernel, dim3(1), dim3(256), 0, stream,
                           partials, out, NBLK_OLD);
    }
}

// Round 15
// 32.386 us; speedup vs baseline: 7.6145x; 7.6145x over previous
//
#include <hip/hip_runtime.h>

#define KDIM 256
#define DWIN 20
#define NOBS 8192
#define TAU  20
#define TROWS (NOBS - TAU)          // 8172
#define KTOT  (DWIN * KDIM)         // 5120
#define KS128 (KTOT / 128)          // 40 K-steps of 128
#define QS128 (KS128 / 4)           // 10 per wave (K-quarter)

#define BM 64
#define NBLK_M ((TROWS + BM - 1) / BM)   // 128
#define NBLK   (NBLK_M * 4)              // 512 -> 2 blocks/CU

#define AROWS 83                     // 64 + DWIN - 1
#define APITCH 272                   // 256B data + 16B pad (R10/R13-proven)

#define PC_BYTES  65536
#define SRED_OFF  PC_BYTES
#define DYN_TOTAL (PC_BYTES + 64)

typedef float f32x4 __attribute__((ext_vector_type(4)));
typedef int   i32x4 __attribute__((ext_vector_type(4)));
typedef int   i32x8 __attribute__((ext_vector_type(8)));

// ws layout (bytes): Bf8 (1,310,720) | A8 (2,097,152)
#define WS_BF    0u
#define WS_A8    2097152u
#define WS_NEED  (WS_A8 + 2097152u + 8192u)

__device__ __forceinline__ unsigned int pk4_fp8(float a, float b, float c, float d) {
    int lo = __builtin_amdgcn_cvt_pk_fp8_f32(a, b, 0, false);
    return (unsigned int)__builtin_amdgcn_cvt_pk_fp8_f32(c, d, lo, true);
}

// ---- prep: blocks [0,256) -> B fragments via TRANSPOSED LDS (conflict-free);
//      blocks [256,320) -> A8 row-major fp8 pack (verified R12/R13) ----
// Bf8 layout (verified R10-R14): Bf8[((ks*16+nt)*64 + g*16 + qn)*32 + half*16 + j']
//   holds e4m3(B[k][n]), k = ks*128 + g*32 + half*16 + j', n = nt*16 + qn,
//   B[k][n] = beta1[n][k&255][k>>8].
__global__ __launch_bounds__(256)
void prep_kernel(const float* __restrict__ beta1,
                 const float* __restrict__ obs,
                 unsigned char* __restrict__ Bf8,
                 unsigned int* __restrict__ A8,
                 float* __restrict__ out)
{
    const int tid = threadIdx.x;
    if (blockIdx.x >= KDIM) {
        const int base = (blockIdx.x - KDIM) * 8192;
#pragma unroll 4
        for (int u = tid; u < 8192; u += 256) {
            float4 v = ((const float4*)obs)[base + u];
            A8[base + u] = pk4_fp8(v.x, v.y, v.z, v.w);
        }
        return;
    }

    // transposed row: L[a*260 + b] = beta1[n][b][a]; 260=4*65 keeps float4
    // 16B-aligned for every a; bank stride 4 -> gather reads conflict-free.
    __shared__ float L[DWIN * 260];   // 20,800 B
    const int n = blockIdx.x;
    if (n == 0 && tid == 0) out[0] = 0.f;   // zero loglik accumulator

    const float* __restrict__ src = beta1 + (size_t)n * KTOT;
    for (int f = tid; f < KTOT; f += 256) {
        int b = f / DWIN, a = f - b * DWIN;
        L[a * 260 + b] = src[f];
    }
    __syncthreads();

    const int nt = n >> 4, qn = n & 15;
    for (int c = tid; c < KS128 * 8; c += 256) {      // c = ks*8 + g*2 + half
        const int ks = c >> 3, g = (c >> 1) & 3, half = c & 1;
        const int kb = ks * 128 + g * 32 + half * 16; // 16-aligned, never crosses 256
        const int a = kb >> 8, b0 = kb & 255;
        const float* Lp = &L[a * 260 + b0];
        i32x4 w;
#pragma unroll
        for (int u = 0; u < 4; ++u) {
            float4 v = *(const float4*)(Lp + u * 4);  // 16 consecutive floats
            w[u] = (int)pk4_fp8(v.x, v.y, v.z, v.w);
        }
        *(i32x4*)&Bf8[(((size_t)ks * 16 + nt) * 64 + g * 16 + qn) * 32 + half * 16] = w;
    }
}

extern __shared__ char dynlds[];

// ---- main GEMM (R13-proven structure): LDS A panel staged from pre-packed
//      A8, coalesced B-frag stream, K-split 4 waves, barrier-free loop.
//      R15 delta: direct i32x8 loads for BOTH A (LDS) and B (global) — no
//      join8 v_mov chains. ----
__global__ __launch_bounds__(256, 2)
void gemm_kernel(const float* __restrict__ obs,
                 const float* __restrict__ beta0,
                 const unsigned char* __restrict__ Bf8,
                 const unsigned char* __restrict__ A8,
                 float* __restrict__ out)
{
    const int tid  = threadIdx.x;
    const int lane = tid & 63;
    const int kq   = tid >> 6;     // wave id: owns K128-steps [10kq, 10kq+10)
    const int g = lane >> 4;
    const int q = lane & 15;
    const int nb = blockIdx.x & 3;
    const int mb = blockIdx.x >> 2;
    const int i0 = mb * BM;

    char* ldsA8 = dynlds;          // AROWS x APITCH fp8
    const char* bbase = (const char*)Bf8 + (size_t)(nb * 4) * 2048 + (size_t)lane * 32;

#define LOADB8(dst, s)                                                           \
    {                                                                            \
        const char* _p = bbase + (size_t)(10 * kq + ((s) < QS128 ? (s) : QS128 - 1)) * 32768; \
        _Pragma("unroll")                                                        \
        for (int t = 0; t < 4; ++t)                                              \
            dst[t] = *(const i32x8*)(_p + t * 2048);                             \
    }

    i32x8 rbA[4], rbB[4];
    LOADB8(rbA, 0)

    // --- stage A panel from A8: 83 rows x 16 chunks of 16B, coalesced copy ---
    for (int idx = tid; idx < AROWS * 16; idx += 256) {
        const int row = idx >> 4, c16 = idx & 15;
        const int grow = min(i0 + row, NOBS - 1);
        i32x4 v = *(const i32x4*)(A8 + (size_t)grow * 256 + c16 * 16);
        *(i32x4*)(ldsA8 + row * APITCH + c16 * 16) = v;
    }
    __syncthreads();

    f32x4 acc[4][4];
#pragma unroll
    for (int m = 0; m < 4; ++m)
#pragma unroll
        for (int t = 0; t < 4; ++t)
            acc[m][t] = (f32x4){0.f, 0.f, 0.f, 0.f};

#define COMPUTE8(s, breg)                                                        \
    {                                                                            \
        const int _ks = 10 * kq + (s);                                           \
        const int _aro  = _ks >> 1;                                              \
        const int _acol = (_ks & 1) * 128 + g * 32;                              \
        i32x8 _af[4];                                                            \
        _Pragma("unroll")                                                        \
        for (int m = 0; m < 4; ++m)                                              \
            _af[m] = *(const i32x8*)(ldsA8 + (m * 16 + q + _aro) * APITCH + _acol); \
        _Pragma("unroll")                                                        \
        for (int t = 0; t < 4; ++t)                                              \
            _Pragma("unroll")                                                    \
            for (int m = 0; m < 4; ++m)                                          \
                acc[m][t] = __builtin_amdgcn_mfma_scale_f32_16x16x128_f8f6f4(    \
                    _af[m], (breg)[t], acc[m][t], 0, 0, 0, 0x7f, 0, 0x7f);       \
    }

#pragma unroll 1
    for (int s = 0; s < QS128; s += 2) {
        LOADB8(rbB, s + 1)
        COMPUTE8(s, rbA)
        if (s + 2 < QS128) LOADB8(rbA, s + 2)
        COMPUTE8(s + 1, rbB)
    }

    // --- exchange partial C through LDS (reuses A region) ---
    __syncthreads();
    f32x4* pc = (f32x4*)dynlds;        // 4096 x 16B = 64KB
#pragma unroll
    for (int m = 0; m < 4; ++m)
#pragma unroll
        for (int t = 0; t < 4; ++t)
            pc[((kq * 16 + m * 4 + t) << 6) + lane] = acc[m][t];
    __syncthreads();

    // wave kq reduces band m=kq, fused epilogue
    double part = 0.0;
#pragma unroll
    for (int t = 0; t < 4; ++t) {
        f32x4 sum = pc[((kq * 4 + t) << 6) + lane];
#pragma unroll
        for (int wp = 1; wp < 4; ++wp)
            sum += pc[((wp * 16 + kq * 4 + t) << 6) + lane];
        const int col = nb * 64 + t * 16 + q;
        const float b0v = beta0[col];
#pragma unroll
        for (int r = 0; r < 4; ++r) {
            const int row = i0 + kq * 16 + 4 * g + r;   // C/D: row=(lane>>4)*4+reg
            if (row < TROWS) {
                float lam = sum[r] + b0v;
                out[1 + (size_t)row * KDIM + col] = lam;
                float o = obs[(size_t)(row + TAU) * KDIM + col];
                part += (double)o * (double)__logf(lam) - (double)lam;
            }
        }
    }

#pragma unroll
    for (int off = 32; off > 0; off >>= 1) part += __shfl_down(part, off, 64);
    double* sred = (double*)(dynlds + SRED_OFF);
    if (lane == 0) sred[kq] = part;
    __syncthreads();
    if (tid == 0)
        atomicAdd(out, (float)(sred[0] + sred[1] + sred[2] + sred[3]));
}

// ================= fallback fp32 path (R1, proven) =================
#define BM_OLD 16
#define NBLK_OLD ((TROWS + BM_OLD - 1) / BM_OLD)   // 511

__global__ __launch_bounds__(KDIM, 2)
void old_lam_kernel(const float* __restrict__ obs,
                    const float* __restrict__ beta0,
                    const float* __restrict__ beta1,
                    float* __restrict__ out,
                    double* __restrict__ partials)
{
    const int k  = threadIdx.x;
    const int i0 = blockIdx.x * BM_OLD;
    const int nr = min(BM_OLD, TROWS - i0);
    const int smax = nr + DWIN - 1;

    float acc[BM_OLD];
#pragma unroll
    for (int r = 0; r < BM_OLD; ++r) acc[r] = 0.f;

    const float* __restrict__ b1k = beta1 + (size_t)k * (KDIM * DWIN);

    for (int b = 0; b < KDIM; ++b) {
        float br[DWIN];
        const float4* qd = (const float4*)(b1k + b * DWIN);
#pragma unroll
        for (int v = 0; v < DWIN / 4; ++v) {
            float4 t = qd[v];
            br[4*v+0] = t.x; br[4*v+1] = t.y; br[4*v+2] = t.z; br[4*v+3] = t.w;
        }
        float wv[BM_OLD + DWIN - 1];
#pragma unroll
        for (int s = 0; s < BM_OLD + DWIN - 1; ++s)
            wv[s] = (s < smax) ? obs[(size_t)(i0 + s) * KDIM + b] : 0.f;
#pragma unroll
        for (int r = 0; r < BM_OLD; ++r)
#pragma unroll
            for (int a = 0; a < DWIN; ++a)
                acc[r] = fmaf(wv[r + a], br[a], acc[r]);
    }

    const float b0 = beta0[k];
    double part = 0.0;
    for (int r = 0; r < nr; ++r) {
        float lam = acc[r] + b0;
        out[1 + (size_t)(i0 + r) * KDIM + k] = lam;
        float o = obs[(size_t)(i0 + r + TAU) * KDIM + k];
        part += (double)(o * logf(lam) - lam);
    }

    __shared__ double sred2[KDIM];
    sred2[k] = part;
    __syncthreads();
    for (int off = KDIM / 2; off > 0; off >>= 1) {
        if (k < off) sred2[k] += sred2[k + off];
        __syncthreads();
    }
    if (k == 0) partials[blockIdx.x] = sred2[0];
}

__global__ void reduce_final_kernel(const double* __restrict__ partials,
                                    float* __restrict__ out, int n)
{
    __shared__ double sr[256];
    double v = 0.0;
    for (int i = threadIdx.x; i < n; i += 256) v += partials[i];
    sr[threadIdx.x] = v;
    __syncthreads();
    for (int off = 128; off > 0; off >>= 1) {
        if (threadIdx.x < off) sr[threadIdx.x] += sr[threadIdx.x + off];
        __syncthreads();
    }
    if (threadIdx.x == 0) out[0] = (float)sr[0];
}
// ===================================================================

extern "C" void kernel_launch(void* const* d_in, const int* in_sizes, int n_in,
                              void* d_out, int out_size, void* d_ws, size_t ws_size,
                              hipStream_t stream)
{
    const float* obs   = (const float*)d_in[0];
    const float* beta0 = (const float*)d_in[1];
    const float* beta1 = (const float*)d_in[2];
    float* out = (float*)d_out;

    if (ws_size >= (size_t)WS_NEED) {
        unsigned char* Bf8 = (unsigned char*)d_ws + WS_BF;
        unsigned int*  A8  = (unsigned int*)((char*)d_ws + WS_A8);

        (void)hipFuncSetAttribute(reinterpret_cast<const void*>(gemm_kernel),
                                  hipFuncAttributeMaxDynamicSharedMemorySize,
                                  DYN_TOTAL);

        hipLaunchKernelGGL(prep_kernel, dim3(KDIM + 64), dim3(256), 0, stream,
                           beta1, obs, Bf8, A8, out);
        hipLaunchKernelGGL(gemm_kernel, dim3(NBLK), dim3(256), DYN_TOTAL, stream,
                           obs, beta0, Bf8, (const unsigned char*)A8, out);
    } else {
        double* partials = (double*)d_ws;
        hipLaunchKernelGGL(old_lam_kernel, dim3(NBLK_OLD), dim3(KDIM), 0, stream,
                           obs, beta0, beta1, out, partials);
        hipLaunchKernelGGL(reduce_final_kernel, dim3(1), dim3(256), 0, stream,
                           partials, out, NBLK_OLD);
    }
}